// Round 4
// baseline (2005.488 us; speedup 1.0000x reference)
//
#include <hip/hip_runtime.h>
#include <stdint.h>
#include <math.h>

// DialogueSNN: B=8, S=256, V=32000, E=64, H=128, T=20 inner steps.
// All internal math in f64 to track the high-precision numpy reference
// (spike outputs are binary: one flipped threshold decision = absmax 1.0).
//
// Pipeline:
//   k0: cur1[t][b][h] = embed[x[b,t]] . W1[:,h] + b1[h]      (fully parallel)
//   k1: layer-1 LIF recursion over 5120 steps, 1024 chains; emits 128-bit
//       spike masks per (t,step,b) via __ballot (wave = (b, half of H))
//   k2: layer-2 LIF recursion; per v-column chain, cur2 = b2[v] + masked
//       row-sum of W2 (mask is wave-uniform -> scalar bit loop, LDS-resident
//       W2 slice). Mask loads double-buffered in registers so the ~200cy
//       L2 latency hides under the bit-loop + f64 update of the prior step.
//
// Recursion uses explicit fma(0.95, m, cur) - r: shortest dependent chain
// (fma->sub), rounding diff vs np's mul+add+sub ~1e-16 (flip-safe in f64).
//
// Workspace: cur1 (256*8*128 f64 = 2 MB) + masks (5120*16 u64 = 640 KB).

#define BB 8
#define SS 256
#define EE 64
#define HH 128
#define VV 32000
#define TT 20
#define NG (SS*TT)   // 5120 total steps

#define TBV 128      // v-columns per block in k2 (LDS slice = 128*128*4 = 64 KB)
#define BSP 4        // batch chains per thread in k2

typedef unsigned long long u64;

__global__ __launch_bounds__(HH) void k0_cur1(
    const int* __restrict__ x, const float* __restrict__ embed,
    const float* __restrict__ W1, const float* __restrict__ b1,
    double* __restrict__ cur1)
{
    int blk = blockIdx.x;          // t*BB + b
    int t = blk >> 3, b = blk & 7;
    int h = threadIdx.x;           // 0..127
    int ix = x[b*SS + t];
    const float* erow = embed + (size_t)ix * EE;
    double acc = 0.0;
    #pragma unroll
    for (int e = 0; e < EE; ++e)
        acc += (double)erow[e] * (double)W1[e*HH + h];
    acc += (double)b1[h];
    cur1[((size_t)t*BB + b)*HH + h] = acc;
}

__global__ __launch_bounds__(64) void k1_l1(
    const double* __restrict__ cur1, u64* __restrict__ masks,
    float* __restrict__ out_mem1)
{
    // one wave per block; blockIdx.x = b*2 + half; lane = h within half
    int b = blockIdx.x >> 1, half = blockIdx.x & 1;
    int lane = threadIdx.x;
    int h = half*64 + lane;
    double m = 0.0;
    double r = 0.0;   // reset at step s == spk at step s-1; heaviside(0-1)=0 init
    for (int t = 0; t < SS; ++t) {
        double cur = cur1[((size_t)t*BB + b)*HH + h];
        #pragma unroll
        for (int s = 0; s < TT; ++s) {
            m = __builtin_fma(0.95, m, cur) - r;   // chain: fma -> sub
            bool spk = m > 1.0;
            r = spk ? 1.0 : 0.0;
            u64 msk = __ballot(spk);
            if (lane == 0) masks[(size_t)(t*TT + s)*(2*BB) + b*2 + half] = msk;
        }
    }
    out_mem1[b*HH + h] = (float)m;
}

__global__ __launch_bounds__(TBV) void k2_l2(
    const float* __restrict__ W2, const float* __restrict__ b2,
    const u64* __restrict__ masks, float* __restrict__ out)
{
    __shared__ float w2s[HH][TBV];   // 64 KB, resident for all 5120 steps
    int tid = threadIdx.x;
    int v0 = blockIdx.x * TBV;
    int b0 = blockIdx.y * BSP;
    for (int i = tid; i < HH*TBV; i += TBV) {
        int hh = i >> 7;             // i / TBV (tid < 128)
        w2s[hh][tid] = W2[(size_t)hh*VV + v0 + tid];
    }
    __syncthreads();

    double mm[BSP], rr[BSP];
    #pragma unroll
    for (int j = 0; j < BSP; ++j) { mm[j] = 0.0; rr[j] = 0.0; }
    const int v = v0 + tid;
    const double b2v = (double)b2[v];

    // mask register double-buffer: cm = step g, nm = step g+1 (issued early)
    u64 cm[2*BSP], nm[2*BSP];
    #pragma unroll
    for (int j = 0; j < BSP; ++j) {
        cm[2*j]   = masks[(size_t)(b0 + j)*2];
        cm[2*j+1] = masks[(size_t)(b0 + j)*2 + 1];
    }

    for (int g = 0; g < NG; ++g) {
        // issue next step's mask loads first (clamped, branch-free)
        size_t gn = (size_t)((g + 1 < NG) ? g + 1 : g) * (2*BB);
        #pragma unroll
        for (int j = 0; j < BSP; ++j) {
            nm[2*j]   = masks[gn + (b0 + j)*2];
            nm[2*j+1] = masks[gn + (b0 + j)*2 + 1];
        }

        bool emit = ((g + 1) % TT) == 0;   // last inner step of this t
        int t = g / TT;
        #pragma unroll
        for (int j = 0; j < BSP; ++j) {
            u64 m0 = cm[2*j], m1 = cm[2*j+1];
            double sum = 0.0;
            while (m0) { int hh = __builtin_ctzll(m0); m0 &= (m0 - 1);
                         sum += (double)w2s[hh][tid]; }
            while (m1) { int hh = __builtin_ctzll(m1); m1 &= (m1 - 1);
                         sum += (double)w2s[64 + hh][tid]; }
            double cur = sum + b2v;                    // matches np op order
            mm[j] = __builtin_fma(0.95, mm[j], cur) - rr[j];
            bool spk = mm[j] > 1.0;
            rr[j] = spk ? 1.0 : 0.0;
            if (emit)
                out[(size_t)(b0 + j)*SS*VV + (size_t)t*VV + v] = spk ? 1.0f : 0.0f;
        }
        #pragma unroll
        for (int j = 0; j < 2*BSP; ++j) cm[j] = nm[j];
    }
    float* mem2out = out + (size_t)BB*SS*VV + (size_t)BB*HH;
    #pragma unroll
    for (int j = 0; j < BSP; ++j)
        mem2out[(size_t)(b0 + j)*VV + v] = (float)mm[j];
}

extern "C" void kernel_launch(void* const* d_in, const int* in_sizes, int n_in,
                              void* d_out, int out_size, void* d_ws, size_t ws_size,
                              hipStream_t stream)
{
    const int*   x     = (const int*)  d_in[0];
    const float* embed = (const float*)d_in[1];
    const float* W1    = (const float*)d_in[2];
    const float* b1    = (const float*)d_in[3];
    const float* W2    = (const float*)d_in[4];
    const float* b2    = (const float*)d_in[5];
    float* out = (float*)d_out;

    // workspace carve: cur1 f64 [256*8*128] then masks u64 [5120*16]
    double* cur1 = (double*)d_ws;
    u64* masks = (u64*)((char*)d_ws + (size_t)SS*BB*HH*sizeof(double));

    k0_cur1<<<SS*BB, HH, 0, stream>>>(x, embed, W1, b1, cur1);
    k1_l1<<<BB*2, 64, 0, stream>>>(cur1, masks, out + (size_t)BB*SS*VV);
    k2_l2<<<dim3(VV/TBV, BB/BSP), TBV, 0, stream>>>(W2, b2, masks, out);
}